// Round 8
// baseline (652.329 us; speedup 1.0000x reference)
//
#include <hip/hip_runtime.h>

#define N_NODES 100000
#define N_EDGES 3200000
#define D_NODE  64
#define OUT_DIM 64

#define FPSCALE     524288.0f           // 2^19
#define INV_FPSCALE 1.9073486328125e-6f // 2^-19

// ---- bucketed staging geometry ----
#define CHUNK   2048                                  // edges per bin-block
#define NCHUNK  ((N_EDGES + CHUNK - 1) / CHUNK)       // 1563
#define NBUCK   49                                    // bucket = node >> 11 (2048 nodes/bucket)
#define CAP     128                                   // slots per (bucket,chunk) cell; mean ~84
#define NQ      4                                     // chunk-quarters per bucket in reduce
#define CPQ     ((NCHUNK + NQ - 1) / NQ)              // 391

// ---------------- prep: zero net4[4]+ovf (contiguous 5*N i64) + compact V[:, :2] ----------------
__global__ __launch_bounds__(256) void prep_kernel(const float* __restrict__ V_node,
                                                   float* __restrict__ V2,
                                                   long long* __restrict__ acc5) {
    int i = blockIdx.x * 256 + threadIdx.x;
    if (i < 5 * N_NODES) acc5[i] = 0LL;
    if (i < N_NODES) {
        const float2 v = *reinterpret_cast<const float2*>(V_node + (size_t)i * D_NODE);
        reinterpret_cast<float2*>(V2)[i] = v;
    }
}

// ---------------- shared edge math ----------------
__device__ __forceinline__ long long edge_pk(const int* __restrict__ senders,
                                             const int* __restrict__ receivers,
                                             const float* __restrict__ EF,
                                             const float* __restrict__ V2,
                                             const float (&w)[20][2], float b0, float b1,
                                             float* __restrict__ Ipred,
                                             int e, int& r_out, int& s_out) {
    int s = senders[e];
    int r = receivers[e];
    r_out = r; s_out = s;
    float2 vr = reinterpret_cast<const float2*>(V2)[r];
    float2 vs = reinterpret_cast<const float2*>(V2)[s];
    float vre = vr.x - vs.x;
    float vim = vr.y - vs.y;
    const float4* EF4 = reinterpret_cast<const float4*>(EF) + (size_t)e * 4;
    float4 f0 = EF4[0], f1 = EF4[1], f2 = EF4[2], f3 = EF4[3];
    float G = f0.x, B = f0.y;
    float ire = G * vre - B * vim;
    float iim = G * vim + B * vre;
    float ei[20] = {vre, vim,
                    f0.x, f0.y, f0.z, f0.w,
                    f1.x, f1.y, f1.z, f1.w,
                    f2.x, f2.y, f2.z, f2.w,
                    f3.x, f3.y, f3.z, f3.w,
                    ire, iim};
    float p0 = ire + b0;
    float p1 = iim + b1;
    #pragma unroll
    for (int k = 0; k < 20; ++k) {
        p0 = fmaf(ei[k], w[k][0], p0);
        p1 = fmaf(ei[k], w[k][1], p1);
    }
    float2 ip = make_float2(p0, p1);
    __builtin_nontemporal_store(__builtin_bit_cast(unsigned long long, ip),
                                reinterpret_cast<unsigned long long*>(Ipred) + e);
    long long fx0 = (long long)__float2int_rn(p0 * FPSCALE);
    long long fx1 = (long long)__float2int_rn(p1 * FPSCALE);
    return (fx1 << 32) + fx0;   // exact packed fixed-point; decode corrects lo-borrow
}

// ---------------- main path: bin records into (bucket,chunk) cells, no global atomics ----------------
__global__ __launch_bounds__(256) void edge_bin_kernel(const int* __restrict__ senders,
                                                       const int* __restrict__ receivers,
                                                       const float* __restrict__ EF,
                                                       const float* __restrict__ V2,
                                                       const float* __restrict__ W_res,
                                                       const float* __restrict__ b_res,
                                                       float* __restrict__ Ipred,
                                                       long long* __restrict__ T_pk,
                                                       unsigned* __restrict__ T_nd,
                                                       unsigned* __restrict__ counts,
                                                       long long* __restrict__ ovf) {
    __shared__ unsigned cursor[NBUCK];
    const int t = threadIdx.x;
    const int c = blockIdx.x;
    if (t < NBUCK) cursor[t] = 0u;
    __syncthreads();

    float b0 = b_res[0], b1 = b_res[1];
    float w[20][2];
    #pragma unroll
    for (int k = 0; k < 20; ++k) { w[k][0] = W_res[k * 2 + 0]; w[k][1] = W_res[k * 2 + 1]; }

    #pragma unroll 2
    for (int i = 0; i < CHUNK / 256; ++i) {
        int e = c * CHUNK + i * 256 + t;
        if (e >= N_EDGES) break;
        int r, s;
        long long pk = edge_pk(senders, receivers, EF, V2, w, b0, b1, Ipred, e, r, s);
        // receiver: +pk
        {
            int b = r >> 11;
            unsigned pos = atomicAdd(&cursor[b], 1u);
            if (pos < CAP) {
                size_t cell = ((size_t)b * NCHUNK + c) * CAP + pos;
                T_pk[cell] = pk;
                T_nd[cell] = (unsigned)r;
            } else {
                atomicAdd((unsigned long long*)(ovf + r), (unsigned long long)pk);
            }
        }
        // sender: -pk
        {
            int b = s >> 11;
            unsigned pos = atomicAdd(&cursor[b], 1u);
            if (pos < CAP) {
                size_t cell = ((size_t)b * NCHUNK + c) * CAP + pos;
                T_pk[cell] = -pk;
                T_nd[cell] = (unsigned)s;
            } else {
                atomicAdd((unsigned long long*)(ovf + s), (unsigned long long)(-pk));
            }
        }
    }
    __syncthreads();
    if (t < NBUCK) counts[(size_t)t * NCHUNK + c] = min(cursor[t], (unsigned)CAP);
}

// ---------------- reduce: per (bucket, chunk-quarter) LDS accumulate, plain-store partials ----------------
__global__ __launch_bounds__(256) void reduce_kernel(const long long* __restrict__ T_pk,
                                                     const unsigned* __restrict__ T_nd,
                                                     const unsigned* __restrict__ counts,
                                                     long long* __restrict__ net4) {
    __shared__ long long acc[2048];
    const int t = threadIdx.x;
    const int B = blockIdx.x / NQ;
    const int q = blockIdx.x % NQ;
    for (int n = t; n < 2048; n += 256) acc[n] = 0LL;
    __syncthreads();

    const int c0 = q * CPQ;
    const int c1 = (c0 + CPQ < NCHUNK) ? c0 + CPQ : NCHUNK;
    for (int c = c0; c < c1; ++c) {
        unsigned cnt = counts[(size_t)B * NCHUNK + c];
        size_t base = ((size_t)B * NCHUNK + c) * CAP;
        for (unsigned j = t; j < cnt; j += 256) {
            long long pk = T_pk[base + j];
            unsigned nd = T_nd[base + j];
            atomicAdd((unsigned long long*)&acc[nd & 2047], (unsigned long long)pk);
        }
    }
    __syncthreads();
    for (int n = t; n < 2048; n += 256) {
        int node = (B << 11) + n;
        if (node < N_NODES) net4[(size_t)q * N_NODES + node] = acc[n];
    }
}

// ---------------- fallback: direct packed global atomics (proven r4 path) ----------------
__global__ __launch_bounds__(256) void edge_atomic_kernel(const int* __restrict__ senders,
                                                          const int* __restrict__ receivers,
                                                          const float* __restrict__ EF,
                                                          const float* __restrict__ V2,
                                                          const float* __restrict__ W_res,
                                                          const float* __restrict__ b_res,
                                                          float* __restrict__ Ipred,
                                                          long long* __restrict__ net0) {
    int e = blockIdx.x * 256 + threadIdx.x;
    if (e >= N_EDGES) return;
    float b0 = b_res[0], b1 = b_res[1];
    float w[20][2];
    #pragma unroll
    for (int k = 0; k < 20; ++k) { w[k][0] = W_res[k * 2 + 0]; w[k][1] = W_res[k * 2 + 1]; }
    int r, s;
    long long pk = edge_pk(senders, receivers, EF, V2, w, b0, b1, Ipred, e, r, s);
    atomicAdd((unsigned long long*)(net0 + r), (unsigned long long)pk);
    atomicAdd((unsigned long long*)(net0 + s), (unsigned long long)(-pk));
}

// ---------------- node phase: out = relu([V_node | net] @ W_node + b) ----------------
#define A_STRIDE 68

__global__ __launch_bounds__(256) void node_kernel(const float* __restrict__ V_node,
                                                   const long long* __restrict__ acc5,
                                                   const float* __restrict__ W_node,
                                                   const float* __restrict__ b_node,
                                                   float* __restrict__ out) {
    __shared__ __align__(16) float Wl[66 * 64];
    __shared__ __align__(16) float Al[64 * A_STRIDE];
    const int t  = threadIdx.x;
    const int n0 = blockIdx.x * 64;

    for (int i = t; i < 66 * 64; i += 256) Wl[i] = W_node[i];

    {
        const float4* Vg  = reinterpret_cast<const float4*>(V_node);
        float4*       Al4 = reinterpret_cast<float4*>(Al);
        #pragma unroll
        for (int q = 0; q < 4; ++q) {
            int f    = t + 256 * q;
            int node = f >> 4;
            int c4   = f & 15;
            int ng   = n0 + node;
            float4 v = (ng < N_NODES) ? Vg[(size_t)ng * 16 + c4]
                                      : make_float4(0.f, 0.f, 0.f, 0.f);
            Al4[node * (A_STRIDE / 4) + c4] = v;
        }
    }
    // sum the 5 partial copies (4 quarters + overflow), decode exact packed fixed-point
    if (t < 64) {
        int ng = n0 + t;
        float c0 = 0.f, c1 = 0.f;
        if (ng < N_NODES) {
            long long a = 0;
            #pragma unroll
            for (int x = 0; x < 5; ++x) a += acc5[(size_t)x * N_NODES + ng];
            int s0 = (int)(unsigned int)(a & 0xffffffffLL);
            int s1 = (int)(a >> 32) + (s0 < 0 ? 1 : 0);
            c0 = (float)s0 * INV_FPSCALE;
            c1 = (float)s1 * INV_FPSCALE;
        }
        Al[t * A_STRIDE + 64] = c0;
        Al[t * A_STRIDE + 65] = c1;
    }
    __syncthreads();

    const int tcol = t & 15;
    const int trow = t >> 4;
    float4 bj = reinterpret_cast<const float4*>(b_node)[tcol];
    float4 acc[4];
    #pragma unroll
    for (int i = 0; i < 4; ++i) acc[i] = bj;

    const float4* Wl4 = reinterpret_cast<const float4*>(Wl);
    #pragma unroll 4
    for (int kc = 0; kc < 64; kc += 4) {
        float a[4][4];
        #pragma unroll
        for (int i = 0; i < 4; ++i) {
            float4 av = *reinterpret_cast<const float4*>(&Al[(trow * 4 + i) * A_STRIDE + kc]);
            a[i][0] = av.x; a[i][1] = av.y; a[i][2] = av.z; a[i][3] = av.w;
        }
        #pragma unroll
        for (int kk = 0; kk < 4; ++kk) {
            float4 wv = Wl4[(kc + kk) * 16 + tcol];
            #pragma unroll
            for (int i = 0; i < 4; ++i) {
                acc[i].x = fmaf(a[i][kk], wv.x, acc[i].x);
                acc[i].y = fmaf(a[i][kk], wv.y, acc[i].y);
                acc[i].z = fmaf(a[i][kk], wv.z, acc[i].z);
                acc[i].w = fmaf(a[i][kk], wv.w, acc[i].w);
            }
        }
    }
    #pragma unroll
    for (int k = 64; k < 66; ++k) {
        float4 wv = Wl4[k * 16 + tcol];
        #pragma unroll
        for (int i = 0; i < 4; ++i) {
            float a = Al[(trow * 4 + i) * A_STRIDE + k];
            acc[i].x = fmaf(a, wv.x, acc[i].x);
            acc[i].y = fmaf(a, wv.y, acc[i].y);
            acc[i].z = fmaf(a, wv.z, acc[i].z);
            acc[i].w = fmaf(a, wv.w, acc[i].w);
        }
    }

    #pragma unroll
    for (int i = 0; i < 4; ++i) {
        int ng = n0 + trow * 4 + i;
        if (ng < N_NODES) {
            float4 o = acc[i];
            o.x = fmaxf(o.x, 0.f);
            o.y = fmaxf(o.y, 0.f);
            o.z = fmaxf(o.z, 0.f);
            o.w = fmaxf(o.w, 0.f);
            reinterpret_cast<float4*>(out)[(size_t)ng * 16 + tcol] = o;
        }
    }
}

extern "C" void kernel_launch(void* const* d_in, const int* in_sizes, int n_in,
                              void* d_out, int out_size, void* d_ws, size_t ws_size,
                              hipStream_t stream) {
    const float* V_node    = (const float*)d_in[0];
    const int*   senders   = (const int*)  d_in[1];
    const int*   receivers = (const int*)  d_in[2];
    const float* EF        = (const float*)d_in[3];
    const float* W_res     = (const float*)d_in[4];
    const float* b_res     = (const float*)d_in[5];
    const float* W_node    = (const float*)d_in[6];
    const float* b_node    = (const float*)d_in[7];

    float* out   = (float*)d_out;
    float* Vout  = out;                                   // N_NODES * 64
    float* Ipred = out + (size_t)N_NODES * OUT_DIM;       // N_EDGES * 2

    // ws layout: acc5 (net4[4]+ovf, 5*N i64) | V2 | T_pk | T_nd | counts
    const size_t NCELLS = (size_t)NBUCK * NCHUNK;         // 76,587
    long long* acc5 = (long long*)d_ws;                   // 500000 i64
    long long* net4 = acc5;                               // first 4*N (quarters)
    long long* ovf  = acc5 + (size_t)4 * N_NODES;         // 5th copy (overflow)
    float*     V2   = (float*)(acc5 + (size_t)5 * N_NODES);           // 2*N f32
    long long* T_pk = (long long*)(V2 + (size_t)2 * N_NODES);         // NCELLS*CAP i64
    unsigned*  T_nd = (unsigned*)(T_pk + NCELLS * CAP);               // NCELLS*CAP u32
    unsigned*  counts = T_nd + NCELLS * CAP;                          // NCELLS u32
    size_t req = (size_t)((char*)(counts + NCELLS) - (char*)d_ws);
    bool big = (ws_size >= req);

    prep_kernel<<<(5 * N_NODES + 255) / 256, 256, 0, stream>>>(V_node, V2, acc5);
    if (big) {
        edge_bin_kernel<<<NCHUNK, 256, 0, stream>>>(senders, receivers, EF, V2,
                                                    W_res, b_res, Ipred,
                                                    T_pk, T_nd, counts, ovf);
        reduce_kernel<<<NBUCK * NQ, 256, 0, stream>>>(T_pk, T_nd, counts, net4);
    } else {
        edge_atomic_kernel<<<(N_EDGES + 255) / 256, 256, 0, stream>>>(senders, receivers, EF, V2,
                                                                      W_res, b_res, Ipred, net4);
    }
    node_kernel<<<(N_NODES + 63) / 64, 256, 0, stream>>>(V_node, acc5, W_node, b_node, Vout);
}

// Round 9
// 455.358 us; speedup vs baseline: 1.4326x; 1.4326x over previous
//
#include <hip/hip_runtime.h>

#define N_NODES 100000
#define N_EDGES 3200000
#define D_NODE  64
#define OUT_DIM 64

#define SCALE18     262144.0f            // 2^18
#define INV_SCALE18 3.814697265625e-6f   // 2^-18
#define PCLAMP      127.99f              // keep fx in 26 signed bits

// ---- bucketed staging geometry ----
#define CHUNK   2048                                  // edges per bin-block
#define NCHUNK  ((N_EDGES + CHUNK - 1) / CHUNK)       // 1563
#define NBUCK   49                                    // bucket = node >> 11
#define CAP     128                                   // slots/cell (mean fill ~84)
#define NQ      16                                    // chunk-slices per bucket in reduce
#define CPQ     ((NCHUNK + NQ - 1) / NQ)              // 98
#define NPART   (NQ + 1)                              // 16 slices + overflow

// ---------------- prep: zero partials + compact V[:, :2] ----------------
__global__ __launch_bounds__(256) void prep_kernel(const float* __restrict__ V_node,
                                                   float* __restrict__ V2,
                                                   long long* __restrict__ acc) {
    int i = blockIdx.x * 256 + threadIdx.x;
    if (i < NPART * N_NODES) acc[i] = 0LL;
    if (i < N_NODES) {
        const float2 v = *reinterpret_cast<const float2*>(V_node + (size_t)i * D_NODE);
        reinterpret_cast<float2*>(V2)[i] = v;
    }
}

// ---------------- shared edge math ----------------
__device__ __forceinline__ void edge_math(const int* __restrict__ senders,
                                          const int* __restrict__ receivers,
                                          const float* __restrict__ EF,
                                          const float* __restrict__ V2,
                                          const float (&w)[20][2], float b0, float b1,
                                          float* __restrict__ Ipred,
                                          int e, int& r, int& s, int& fx0, int& fx1) {
    s = senders[e];
    r = receivers[e];
    float2 vr = reinterpret_cast<const float2*>(V2)[r];
    float2 vs = reinterpret_cast<const float2*>(V2)[s];
    float vre = vr.x - vs.x;
    float vim = vr.y - vs.y;
    const float4* EF4 = reinterpret_cast<const float4*>(EF) + (size_t)e * 4;
    float4 f0 = EF4[0], f1 = EF4[1], f2 = EF4[2], f3 = EF4[3];
    float G = f0.x, B = f0.y;
    float ire = G * vre - B * vim;
    float iim = G * vim + B * vre;
    float ei[20] = {vre, vim,
                    f0.x, f0.y, f0.z, f0.w,
                    f1.x, f1.y, f1.z, f1.w,
                    f2.x, f2.y, f2.z, f2.w,
                    f3.x, f3.y, f3.z, f3.w,
                    ire, iim};
    float p0 = ire + b0;
    float p1 = iim + b1;
    #pragma unroll
    for (int k = 0; k < 20; ++k) {
        p0 = fmaf(ei[k], w[k][0], p0);
        p1 = fmaf(ei[k], w[k][1], p1);
    }
    float2 ip = make_float2(p0, p1);
    __builtin_nontemporal_store(__builtin_bit_cast(unsigned long long, ip),
                                reinterpret_cast<unsigned long long*>(Ipred) + e);
    fx0 = __float2int_rn(fminf(fmaxf(p0, -PCLAMP), PCLAMP) * SCALE18);
    fx1 = __float2int_rn(fminf(fmaxf(p1, -PCLAMP), PCLAMP) * SCALE18);
}

__device__ __forceinline__ unsigned long long enc_rec(int fx0, int fx1, int node) {
    return ((unsigned long long)((unsigned)fx1 & 0x3ffffffu) << 37) |
           ((unsigned long long)((unsigned)fx0 & 0x3ffffffu) << 11) |
           (unsigned long long)(node & 2047);
}

// ---------------- main: compute + LDS-compacted binning + coalesced flush ----------------
__global__ __launch_bounds__(256) void edge_bin_kernel(const int* __restrict__ senders,
                                                       const int* __restrict__ receivers,
                                                       const float* __restrict__ EF,
                                                       const float* __restrict__ V2,
                                                       const float* __restrict__ W_res,
                                                       const float* __restrict__ b_res,
                                                       float* __restrict__ Ipred,
                                                       unsigned long long* __restrict__ T,
                                                       unsigned* __restrict__ counts,
                                                       long long* __restrict__ ovf) {
    __shared__ unsigned long long rec[NBUCK * CAP];   // ~50.2 KB
    __shared__ unsigned cursor[NBUCK];
    const int t = threadIdx.x;
    const int c = blockIdx.x;
    if (t < NBUCK) cursor[t] = 0u;
    __syncthreads();

    float b0 = b_res[0], b1 = b_res[1];
    float w[20][2];
    #pragma unroll
    for (int k = 0; k < 20; ++k) { w[k][0] = W_res[k * 2 + 0]; w[k][1] = W_res[k * 2 + 1]; }

    for (int i = 0; i < CHUNK / 256; ++i) {
        int e = c * CHUNK + i * 256 + t;
        if (e >= N_EDGES) break;
        int r, s, fx0, fx1;
        edge_math(senders, receivers, EF, V2, w, b0, b1, Ipred, e, r, s, fx0, fx1);
        // receiver: +
        {
            int b = r >> 11;
            unsigned pos = atomicAdd(&cursor[b], 1u);
            if (pos < CAP) rec[b * CAP + pos] = enc_rec(fx0, fx1, r);
            else atomicAdd((unsigned long long*)(ovf + r),
                           (unsigned long long)(((long long)fx1 << 32) + (long long)fx0));
        }
        // sender: -
        {
            int b = s >> 11;
            unsigned pos = atomicAdd(&cursor[b], 1u);
            if (pos < CAP) rec[b * CAP + pos] = enc_rec(-fx0, -fx1, s);
            else atomicAdd((unsigned long long*)(ovf + s),
                           (unsigned long long)(((long long)(-fx1) << 32) + (long long)(-fx0)));
        }
    }
    __syncthreads();

    // coalesced flush: wave w handles buckets w, w+4, ...
    const int wave = t >> 6, lane = t & 63;
    for (int b = wave; b < NBUCK; b += 4) {
        unsigned cnt = min(cursor[b], (unsigned)CAP);
        size_t base = ((size_t)b * NCHUNK + c) * CAP;
        for (unsigned j = lane; j < cnt; j += 64)
            T[base + j] = rec[b * CAP + j];
        if (lane == 0) counts[(size_t)b * NCHUNK + c] = cnt;
    }
}

// ---------------- reduce: (bucket, chunk-slice) -> LDS i64 accumulate -> plain store ----------------
__global__ __launch_bounds__(256) void reduce_kernel(const unsigned long long* __restrict__ T,
                                                     const unsigned* __restrict__ counts,
                                                     long long* __restrict__ netq) {
    __shared__ unsigned long long acc[2048];          // 16 KB
    const int t = threadIdx.x;
    const int B = blockIdx.x / NQ;
    const int q = blockIdx.x % NQ;
    for (int n = t; n < 2048; n += 256) acc[n] = 0ULL;
    __syncthreads();

    const int c0 = q * CPQ;
    const int c1 = (c0 + CPQ < NCHUNK) ? c0 + CPQ : NCHUNK;
    for (int c = c0; c < c1; ++c) {
        unsigned cnt = counts[(size_t)B * NCHUNK + c];
        size_t base = ((size_t)B * NCHUNK + c) * CAP;
        for (unsigned j = t; j < cnt; j += 256) {
            unsigned long long rv = T[base + j];
            long long sr  = (long long)rv;
            long long fx1 = (sr << 1)  >> 38;   // sign-extended 26-bit
            long long fx0 = (sr << 27) >> 38;
            int nd = (int)(rv & 2047u);
            atomicAdd(&acc[nd], (unsigned long long)((fx1 << 32) + fx0));
        }
    }
    __syncthreads();
    for (int n = t; n < 2048; n += 256) {
        int node = (B << 11) + n;
        if (node < N_NODES) netq[(size_t)q * N_NODES + node] = (long long)acc[n];
    }
}

// ---------------- fallback: direct packed global atomics into partial 0 ----------------
__global__ __launch_bounds__(256) void edge_atomic_kernel(const int* __restrict__ senders,
                                                          const int* __restrict__ receivers,
                                                          const float* __restrict__ EF,
                                                          const float* __restrict__ V2,
                                                          const float* __restrict__ W_res,
                                                          const float* __restrict__ b_res,
                                                          float* __restrict__ Ipred,
                                                          long long* __restrict__ net0) {
    int e = blockIdx.x * 256 + threadIdx.x;
    if (e >= N_EDGES) return;
    float b0 = b_res[0], b1 = b_res[1];
    float w[20][2];
    #pragma unroll
    for (int k = 0; k < 20; ++k) { w[k][0] = W_res[k * 2 + 0]; w[k][1] = W_res[k * 2 + 1]; }
    int r, s, fx0, fx1;
    edge_math(senders, receivers, EF, V2, w, b0, b1, Ipred, e, r, s, fx0, fx1);
    long long pk = ((long long)fx1 << 32) + (long long)fx0;
    atomicAdd((unsigned long long*)(net0 + r), (unsigned long long)pk);
    atomicAdd((unsigned long long*)(net0 + s), (unsigned long long)(-pk));
}

// ---------------- node phase: out = relu([V_node | net] @ W_node + b) ----------------
#define A_STRIDE 68

__global__ __launch_bounds__(256) void node_kernel(const float* __restrict__ V_node,
                                                   const long long* __restrict__ accp,
                                                   const float* __restrict__ W_node,
                                                   const float* __restrict__ b_node,
                                                   float* __restrict__ out) {
    __shared__ __align__(16) float Wl[66 * 64];
    __shared__ __align__(16) float Al[64 * A_STRIDE];
    const int t  = threadIdx.x;
    const int n0 = blockIdx.x * 64;

    for (int i = t; i < 66 * 64; i += 256) Wl[i] = W_node[i];

    {
        const float4* Vg  = reinterpret_cast<const float4*>(V_node);
        float4*       Al4 = reinterpret_cast<float4*>(Al);
        #pragma unroll
        for (int q = 0; q < 4; ++q) {
            int f    = t + 256 * q;
            int node = f >> 4;
            int c4   = f & 15;
            int ng   = n0 + node;
            float4 v = (ng < N_NODES) ? Vg[(size_t)ng * 16 + c4]
                                      : make_float4(0.f, 0.f, 0.f, 0.f);
            Al4[node * (A_STRIDE / 4) + c4] = v;
        }
    }
    // sum the 17 partials (exact i64), decode packed fixed-point with borrow fix
    if (t < 64) {
        int ng = n0 + t;
        float c0 = 0.f, c1 = 0.f;
        if (ng < N_NODES) {
            long long a = 0;
            #pragma unroll
            for (int x = 0; x < NPART; ++x) a += accp[(size_t)x * N_NODES + ng];
            int s0 = (int)(unsigned int)(a & 0xffffffffLL);
            int s1 = (int)(a >> 32) + (s0 < 0 ? 1 : 0);
            c0 = (float)s0 * INV_SCALE18;
            c1 = (float)s1 * INV_SCALE18;
        }
        Al[t * A_STRIDE + 64] = c0;
        Al[t * A_STRIDE + 65] = c1;
    }
    __syncthreads();

    const int tcol = t & 15;
    const int trow = t >> 4;
    float4 bj = reinterpret_cast<const float4*>(b_node)[tcol];
    float4 acc[4];
    #pragma unroll
    for (int i = 0; i < 4; ++i) acc[i] = bj;

    const float4* Wl4 = reinterpret_cast<const float4*>(Wl);
    #pragma unroll 4
    for (int kc = 0; kc < 64; kc += 4) {
        float a[4][4];
        #pragma unroll
        for (int i = 0; i < 4; ++i) {
            float4 av = *reinterpret_cast<const float4*>(&Al[(trow * 4 + i) * A_STRIDE + kc]);
            a[i][0] = av.x; a[i][1] = av.y; a[i][2] = av.z; a[i][3] = av.w;
        }
        #pragma unroll
        for (int kk = 0; kk < 4; ++kk) {
            float4 wv = Wl4[(kc + kk) * 16 + tcol];
            #pragma unroll
            for (int i = 0; i < 4; ++i) {
                acc[i].x = fmaf(a[i][kk], wv.x, acc[i].x);
                acc[i].y = fmaf(a[i][kk], wv.y, acc[i].y);
                acc[i].z = fmaf(a[i][kk], wv.z, acc[i].z);
                acc[i].w = fmaf(a[i][kk], wv.w, acc[i].w);
            }
        }
    }
    #pragma unroll
    for (int k = 64; k < 66; ++k) {
        float4 wv = Wl4[k * 16 + tcol];
        #pragma unroll
        for (int i = 0; i < 4; ++i) {
            float a = Al[(trow * 4 + i) * A_STRIDE + k];
            acc[i].x = fmaf(a, wv.x, acc[i].x);
            acc[i].y = fmaf(a, wv.y, acc[i].y);
            acc[i].z = fmaf(a, wv.z, acc[i].z);
            acc[i].w = fmaf(a, wv.w, acc[i].w);
        }
    }

    #pragma unroll
    for (int i = 0; i < 4; ++i) {
        int ng = n0 + trow * 4 + i;
        if (ng < N_NODES) {
            float4 o = acc[i];
            o.x = fmaxf(o.x, 0.f);
            o.y = fmaxf(o.y, 0.f);
            o.z = fmaxf(o.z, 0.f);
            o.w = fmaxf(o.w, 0.f);
            reinterpret_cast<float4*>(out)[(size_t)ng * 16 + tcol] = o;
        }
    }
}

extern "C" void kernel_launch(void* const* d_in, const int* in_sizes, int n_in,
                              void* d_out, int out_size, void* d_ws, size_t ws_size,
                              hipStream_t stream) {
    const float* V_node    = (const float*)d_in[0];
    const int*   senders   = (const int*)  d_in[1];
    const int*   receivers = (const int*)  d_in[2];
    const float* EF        = (const float*)d_in[3];
    const float* W_res     = (const float*)d_in[4];
    const float* b_res     = (const float*)d_in[5];
    const float* W_node    = (const float*)d_in[6];
    const float* b_node    = (const float*)d_in[7];

    float* out   = (float*)d_out;
    float* Vout  = out;                                   // N_NODES * 64
    float* Ipred = out + (size_t)N_NODES * OUT_DIM;       // N_EDGES * 2

    // ws layout: accp (17*N i64: 16 slices + ovf) | V2 | counts | T
    const size_t NCELLS = (size_t)NBUCK * NCHUNK;         // 76,587
    long long* accp = (long long*)d_ws;
    long long* netq = accp;                               // slices 0..15
    long long* ovf  = accp + (size_t)NQ * N_NODES;        // slice 16
    float*     V2   = (float*)(accp + (size_t)NPART * N_NODES);
    unsigned*  counts = (unsigned*)(V2 + (size_t)2 * N_NODES);
    unsigned long long* T = (unsigned long long*)(counts + NCELLS);
    size_t req = (size_t)((char*)(T + NCELLS * CAP) - (char*)d_ws);
    bool big = (ws_size >= req);

    prep_kernel<<<(NPART * N_NODES + 255) / 256, 256, 0, stream>>>(V_node, V2, accp);
    if (big) {
        edge_bin_kernel<<<NCHUNK, 256, 0, stream>>>(senders, receivers, EF, V2,
                                                    W_res, b_res, Ipred, T, counts, ovf);
        reduce_kernel<<<NBUCK * NQ, 256, 0, stream>>>(T, counts, netq);
    } else {
        edge_atomic_kernel<<<(N_EDGES + 255) / 256, 256, 0, stream>>>(senders, receivers, EF, V2,
                                                                      W_res, b_res, Ipred, netq);
    }
    node_kernel<<<(N_NODES + 63) / 64, 256, 0, stream>>>(V_node, accp, W_node, b_node, Vout);
}